// Round 15
// baseline (461.660 us; speedup 1.0000x reference)
//
#include <hip/hip_runtime.h>

#define B_ 256
#define T_ 500
#define N_ 256
#define BN_ 65536            // B_*N_
#define STP_ 196608          // 3*B_*N_ (states per-t stride)
#define TW 32                // t-window per chunk
#define NCHUNK 16            // 15 full + one valid=20 chunk

// ---------------------------------------------------------------------------
// Fused GEMM + Izhikevich scan, N-split, 2 blocks/CU. Grid 512 = (batch b,
// neuron-half nh); 256 threads; LDS 48 KB -> TWO co-resident blocks per CU.
// The blocks are barrier-independent: one block's G (LDS/FMA) overlaps the
// other's S (HBM stores) -- the overlap R4..R14 structurally lacked.
// NUMERICS: scan uses the R14-PINNED explicit-__builtin_fmaf text (verbatim),
// so spike decisions are context-immune (R14 proved this: scan rewrite with
// pinned fmaf kept absmax bit-identical). I is bit-identical: 4x4 microtile
// accumulates k strictly ascending 0..255 per output, same chain as R14.
// li readout moved to dec_kernel (reads out_s; tree-order dot, error ~1e-6).
// ---------------------------------------------------------------------------
__global__ __launch_bounds__(256)
void fused_snn_kernel(const float* __restrict__ X, const float* __restrict__ W1,
                      float* __restrict__ out_s, float* __restrict__ states,
                      const float* __restrict__ st_snn,
                      const float* __restrict__ pa, const float* __restrict__ pb,
                      const float* __restrict__ pc, const float* __restrict__ pd,
                      const float* __restrict__ pv0, const float* __restrict__ pv1,
                      const float* __restrict__ pv2, const float* __restrict__ ptau,
                      const float* __restrict__ pth) {
    __shared__ float Al[256 * TW];       // 32 KB: X chunk [k][t]; then Il[t][n]
    __shared__ float Ws[2][16 * 128];    // 16 KB: W1 half-slice double buffer

    const int tid = threadIdx.x;
    const int bb  = blockIdx.x >> 1;     // batch
    const int nh  = blockIdx.x & 1;      // neuron half
    const int n0  = nh << 7;
    const int pn  = n0 + (tid & 127);    // global neuron (scan threads: tid<128)
    const int boff = bb * 256 + pn;

    // scan per-thread state & params (used by tid<128 only)
    float v = st_snn[boff];
    float u = st_snn[BN_ + boff];
    const float a_   = pa[pn];
    const float b_   = pb[pn];
    const float c_   = pc[pn];
    const float d_   = pd[pn];
    const float v0_  = pv0[pn];
    const float v1_  = pv1[pn];
    const float v2_  = pv2[pn];
    const float coef = (1.0f / ptau[pn]) * a_;   // (DT/tau_u)*a, DT=1
    const float th_  = pth[pn];

    // GEMM microtile: 8 t-groups x 32 n-groups, 4x4 per thread
    const int g  = tid >> 5;             // t rows 4g..4g+3
    const int h4 = (tid & 31) << 2;      // local n cols h4..h4+3

    // A-stage map: thread covers t=tl, k = kb + 32r + j
    const int tl = tid & 31;
    const int kb = (tid >> 5) << 2;      // 0,4,...,28

    // W-stage map: thread pair covers local row wn, k sub-offset wk
    const int wn = tid >> 1;             // 0..127
    const int wk = (tid & 1) << 3;       // 0 or 8

    const float* Xb  = X + (size_t)bb * (T_ * 256);
    const float* W1h = W1 + (size_t)n0 * 256;    // rows n0..n0+127

    for (int cc = 0; cc < NCHUNK; ++cc) {
        const int t0    = cc * TW;
        const int valid = (T_ - t0 < TW) ? (T_ - t0) : TW;

        // ---------------- phase A: X chunk -> Al[k][t] ----------------
        {
            const int tsrc = t0 + ((tl < valid) ? tl : (valid - 1));
            const float* Xrow = Xb + (size_t)tsrc * 256;
#pragma unroll
            for (int r = 0; r < 8; ++r) {
                const int k = kb + (r << 5);
                const float4 xv = *(const float4*)(Xrow + k);
                Al[(k + 0) * TW + tl] = xv.x;    // lanes consecutive: conflict-free
                Al[(k + 1) * TW + tl] = xv.y;
                Al[(k + 2) * TW + tl] = xv.z;
                Al[(k + 3) * TW + tl] = xv.w;
            }
        }
        // stage W slice ks=0 into Ws[0]   (Ws[kk][n] = W1[n0+n][kk])
        {
            const float* Wr = W1h + (size_t)wn * 256 + wk;
            const float4 q0 = *(const float4*)(Wr);
            const float4 q1 = *(const float4*)(Wr + 4);
            float* Wd = &Ws[0][0];
            Wd[(wk + 0) * 128 + wn] = q0.x; Wd[(wk + 1) * 128 + wn] = q0.y;
            Wd[(wk + 2) * 128 + wn] = q0.z; Wd[(wk + 3) * 128 + wn] = q0.w;
            Wd[(wk + 4) * 128 + wn] = q1.x; Wd[(wk + 5) * 128 + wn] = q1.y;
            Wd[(wk + 6) * 128 + wn] = q1.z; Wd[(wk + 7) * 128 + wn] = q1.w;
        }
        __syncthreads();

        // ---------------- phase G: block GEMM, acc in regs ----------------
        float acc[4][4];
#pragma unroll
        for (int i = 0; i < 4; ++i)
#pragma unroll
            for (int j = 0; j < 4; ++j) acc[i][j] = 0.f;

        for (int ks = 0; ks < 16; ++ks) {
            float4 q0, q1;
            if (ks < 15) {               // issue next-slice W loads early (L2)
                const float* Wr = W1h + (size_t)wn * 256 + (ks + 1) * 16 + wk;
                q0 = *(const float4*)(Wr);
                q1 = *(const float4*)(Wr + 4);
            }
            const float* Wc = &Ws[ks & 1][0];
            const int kbase = ks << 4;
#pragma unroll
            for (int kk = 0; kk < 16; ++kk) {
                const float4 av = *(const float4*)&Al[(kbase + kk) * TW + (g << 2)];
                const float4 bv = *(const float4*)&Wc[kk * 128 + h4];
                const float avr[4] = {av.x, av.y, av.z, av.w};
                const float bvr[4] = {bv.x, bv.y, bv.z, bv.w};
#pragma unroll
                for (int i = 0; i < 4; ++i)
#pragma unroll
                    for (int j = 0; j < 4; ++j)
                        acc[i][j] += avr[i] * bvr[j];
            }
            if (ks < 15) {               // LDS writes after FMAs (latency hidden)
                float* Wd = &Ws[(ks + 1) & 1][0];
                Wd[(wk + 0) * 128 + wn] = q0.x; Wd[(wk + 1) * 128 + wn] = q0.y;
                Wd[(wk + 2) * 128 + wn] = q0.z; Wd[(wk + 3) * 128 + wn] = q0.w;
                Wd[(wk + 4) * 128 + wn] = q1.x; Wd[(wk + 5) * 128 + wn] = q1.y;
                Wd[(wk + 6) * 128 + wn] = q1.z; Wd[(wk + 7) * 128 + wn] = q1.w;
            }
            __syncthreads();             // also separates ks=15 Al reads from I-write
        }

        // ---------------- phase I: acc -> Al as Il[t][n] ----------------
        float* Il = Al;                  // reuse (GEMM reads done: barrier above)
#pragma unroll
        for (int i = 0; i < 4; ++i)
            *(float4*)&Il[((g << 2) + i) * 128 + h4] =
                make_float4(acc[i][0], acc[i][1], acc[i][2], acc[i][3]);
        __syncthreads();

        // ---------------- phase S: scan (tid<128, R14-PINNED text) ----------
        if (tid < 128) {
            float Inx = Il[tid];         // q=0 prefetch
            for (int q = 0; q < valid; ++q) {
                const float Icur = Inx;
                if (q + 1 < valid) Inx = Il[(q + 1) * 128 + tid];
                const int t = t0 + q;
                const size_t pbase = (size_t)t * STP_ + boff;

                // canonical explicit-fma form (R14 verbatim):
                const float m1 = v2_ * v;
                const float t2 = v1_ * v;
                const float P  = __builtin_fmaf(m1, v, t2);
                const float Q  = (P + v0_) - u;
                const float vm = v + (Q + Icur);
                const float tb = __builtin_fmaf(b_, v, -u);
                const float um = __builtin_fmaf(coef, tb, u);

                const bool  sp = (vm - th_) > 0.f;
                const float s  = sp ? 1.f : 0.f;
                v = sp ? c_ : vm;        // == vm*(1-s)+s*c exactly, s in {0,1}
                u = sp ? (um + d_) : um; // == um + s*d

                states[pbase]           = v;
                states[pbase + BN_]     = u;
                states[pbase + 2 * BN_] = s;
                out_s[(size_t)t * BN_ + boff] = s;
            }
        }
        __syncthreads();                 // Il reads done before next A-stage
    }
}

// ---------------------------------------------------------------------------
// Readout: dots[t] = out_s[t,b,:] . W2, then thread-0 li recurrence.
// One block per batch b; wave w handles t = 4i + w. ~131 MB read.
// Tree-order dot (same class as the R4..R14 passing kernels' dotw trees);
// li has no feedback into the dynamics, reorder error ~1e-6 << 2.54.
// ---------------------------------------------------------------------------
__global__ __launch_bounds__(256)
void dec_kernel(const float* __restrict__ out_s, float* __restrict__ out_dec,
                const float* __restrict__ st_li, const float* __restrict__ W2,
                const float* __restrict__ pleak) {
    __shared__ float dots[T_];
    const int bb   = blockIdx.x;
    const int tid  = threadIdx.x;
    const int w    = tid >> 6;
    const int lane = tid & 63;

    const float4 w2v = *(const float4*)&W2[lane << 2];
    const float* base = out_s + (size_t)bb * 256 + (lane << 2);

    for (int i = 0; i < 125; ++i) {      // 4 waves x 125 = 500 t
        const int t = (i << 2) + w;
        const float4 sv = *(const float4*)(base + (size_t)t * BN_);
        float p = sv.x * w2v.x + sv.y * w2v.y + sv.z * w2v.z + sv.w * w2v.w;
        p += __shfl_xor(p, 1);  p += __shfl_xor(p, 2);
        p += __shfl_xor(p, 4);  p += __shfl_xor(p, 8);
        p += __shfl_xor(p, 16); p += __shfl_xor(p, 32);
        if (lane == 0) dots[t] = p;
    }
    __syncthreads();

    if (tid == 0) {
        const float lk_  = pleak[0];
        const float olk_ = 1.0f - lk_;
        float li = st_li[bb];
        for (int t = 0; t < T_; ++t) {
            li = lk_ * li + olk_ * dots[t];
            out_dec[(size_t)t * 256 + bb] = li;
        }
    }
}

// ---------------------------------------------------------------------------
extern "C" void kernel_launch(void* const* d_in, const int* in_sizes, int n_in,
                              void* d_out, int out_size, void* d_ws, size_t ws_size,
                              hipStream_t stream) {
    const float* input  = (const float*)d_in[0];   // [B,T,N]
    const float* st_snn = (const float*)d_in[1];   // [3,B,N]
    const float* st_li  = (const float*)d_in[2];   // [B,1]
    const float* W1     = (const float*)d_in[3];   // [N,N]
    const float* W2     = (const float*)d_in[4];   // [1,N]
    const float* pa     = (const float*)d_in[5];
    const float* pb     = (const float*)d_in[6];
    const float* pc     = (const float*)d_in[7];
    const float* pd     = (const float*)d_in[8];
    const float* pv0    = (const float*)d_in[9];
    const float* pv1    = (const float*)d_in[10];
    const float* pv2    = (const float*)d_in[11];
    const float* ptau   = (const float*)d_in[12];
    const float* pth    = (const float*)d_in[13];
    const float* pleak  = (const float*)d_in[14];

    float* out        = (float*)d_out;
    float* out_s      = out;                                        // [500,256,256]
    float* out_states = out + (size_t)T_ * BN_;                     // [500,3,256,256]
    float* out_dec    = out + (size_t)T_ * BN_ + (size_t)T_ * STP_; // [500,256]

    fused_snn_kernel<<<dim3(B_ * 2), dim3(256), 0, stream>>>(
        input, W1, out_s, out_states, st_snn,
        pa, pb, pc, pd, pv0, pv1, pv2, ptau, pth);
    dec_kernel<<<dim3(B_), dim3(256), 0, stream>>>(
        out_s, out_dec, st_li, W2, pleak);
}

// Round 16
// 388.285 us; speedup vs baseline: 1.1890x; 1.1890x over previous
//
#include <hip/hip_runtime.h>

#define B_ 256
#define T_ 500
#define N_ 256
#define BN_ 65536            // B_*N_
#define STP_ 196608          // 3*B_*N_ (states per-t stride)
#define TW 64                // t-window per chunk
#define NCHUNK 8             // ceil(500/64)

// Soft barrier: LDS-visibility sync WITHOUT the vmcnt(0) store drain that
// __syncthreads() emits. All cross-thread data in the chunk loop flows via
// LDS (Al/Ws/dotm -> lgkmcnt); the 516 MB of global stores have no in-kernel
// consumer and may drain in the background across phases/chunks.
// sched_barrier(0) fences (rule #18: hipcc can hoist reg-only ops past
// inline-asm waitcnt despite the memory clobber).
#define SOFT_BAR() do {                                   \
    __builtin_amdgcn_sched_barrier(0);                    \
    asm volatile("s_waitcnt lgkmcnt(0)" ::: "memory");    \
    __builtin_amdgcn_s_barrier();                         \
    __builtin_amdgcn_sched_barrier(0);                    \
} while (0)

// ---------------------------------------------------------------------------
// Fused GEMM + Izhikevich scan. One block per batch b (256 blocks x 256 thr).
// R14 kernel (383 us, passing) with ONE change: all chunk-loop barriers are
// SOFT (lgkmcnt-only). R14's 17 __syncthreads per chunk each forced
// s_waitcnt vmcnt(0) -> the scan phase's 4 stores/step (516 MB total) and
// the W-prefetch loads serialized against compute at every barrier.
// Arithmetic text byte-identical to R14 (scan is fmaf-PINNED; I bit-identical).
// ---------------------------------------------------------------------------
__global__ __launch_bounds__(256)
void fused_snn_kernel(const float* __restrict__ X, const float* __restrict__ W1,
                      float* __restrict__ out_s, float* __restrict__ states,
                      float* __restrict__ out_dec,
                      const float* __restrict__ st_snn, const float* __restrict__ st_li,
                      const float* __restrict__ W2,
                      const float* __restrict__ pa, const float* __restrict__ pb,
                      const float* __restrict__ pc, const float* __restrict__ pd,
                      const float* __restrict__ pv0, const float* __restrict__ pv1,
                      const float* __restrict__ pv2, const float* __restrict__ ptau,
                      const float* __restrict__ pth, const float* __restrict__ pleak) {
    __shared__ float Al[TW * 256];              // 64 KB: X (k-major) then I[t][n]
    __shared__ float Ws[2][16 * 256];           // 32 KB: W1t slice double buffer
    __shared__ unsigned long long dotm[T_][4];  // ~16 KB: per-wave spike masks
    __shared__ float dotf[T_][4];               //  8 KB: per-wave dot partials
    __shared__ float w2l[256];                  //  1 KB

    const int bb   = blockIdx.x;
    const int tid  = threadIdx.x;
    const int w    = tid >> 6;
    const int lane = tid & 63;
    const int boff = bb * 256 + tid;

    // scan per-thread state & params
    float v = st_snn[boff];
    float u = st_snn[BN_ + boff];
    const float a_   = pa[tid];
    const float b_   = pb[tid];
    const float c_   = pc[tid];
    const float d_   = pd[tid];
    const float v0_  = pv0[tid];
    const float v1_  = pv1[tid];
    const float v2_  = pv2[tid];
    const float coef = (1.0f / ptau[tid]) * a_;  // (DT/tau_u)*a, DT=1
    const float th_  = pth[tid];
    w2l[tid] = W2[tid];

    // GEMM microtile: 8 t-groups x 32 n-groups, 8x8 per thread
    const int g   = tid >> 5;            // t rows 8g..8g+7
    const int tg  = g << 3;
    const int h4  = (tid & 31) << 2;     // n cols h4..h4+3 and h4+128..h4+131

    const float* Xb = X + (size_t)bb * (T_ * 256);
    const int tl = tid & 63;             // A-stage t_loc
    const int wq = (tid >> 6) << 2;      // A-stage k sub-quad

    // W ks=0 slice held permanently in regs (chunk-invariant)
    const float* Wr0 = W1 + (size_t)tid * 256;
    const float4 z0 = *(const float4*)(Wr0 + 0);
    const float4 z1 = *(const float4*)(Wr0 + 4);
    const float4 z2 = *(const float4*)(Wr0 + 8);
    const float4 z3 = *(const float4*)(Wr0 + 12);

    // async A-stage: prologue issue for chunk 0
    float4 ra[16];
    {
        const int tsrc = ((tl < TW) ? tl : (TW - 1));   // valid=64 for chunk 0
        const float* Xrow = Xb + (size_t)tsrc * 256;
#pragma unroll
        for (int r = 0; r < 16; ++r)
            ra[r] = *(const float4*)(Xrow + r * 16 + wq);
    }

    for (int cc = 0; cc < NCHUNK; ++cc) {
        const int t0    = cc * TW;
        const int valid = (T_ - t0 < TW) ? (T_ - t0) : TW;

        // ---------------- phase A: regs -> Al[k][t] (write-late) ------------
#pragma unroll
        for (int r = 0; r < 16; ++r) {
            const int k = r * 16 + wq;
            Al[(k + 0) * 64 + tl] = ra[r].x;
            Al[(k + 1) * 64 + tl] = ra[r].y;
            Al[(k + 2) * 64 + tl] = ra[r].z;
            Al[(k + 3) * 64 + tl] = ra[r].w;
        }
        // stage W slice ks=0 into Ws[0] from held regs (Ws[kk][n]=W1[n][kk])
        {
            float* Wd = &Ws[0][0];
            Wd[ 0*256+tid]=z0.x; Wd[ 1*256+tid]=z0.y; Wd[ 2*256+tid]=z0.z; Wd[ 3*256+tid]=z0.w;
            Wd[ 4*256+tid]=z1.x; Wd[ 5*256+tid]=z1.y; Wd[ 6*256+tid]=z1.z; Wd[ 7*256+tid]=z1.w;
            Wd[ 8*256+tid]=z2.x; Wd[ 9*256+tid]=z2.y; Wd[10*256+tid]=z2.z; Wd[11*256+tid]=z2.w;
            Wd[12*256+tid]=z3.x; Wd[13*256+tid]=z3.y; Wd[14*256+tid]=z3.z; Wd[15*256+tid]=z3.w;
        }
        SOFT_BAR();

        // ---------------- phase G: block GEMM, 8x8 acc in regs --------------
        float acc[8][8];
#pragma unroll
        for (int i = 0; i < 8; ++i)
#pragma unroll
            for (int j = 0; j < 8; ++j) acc[i][j] = 0.f;

        for (int ks = 0; ks < 16; ++ks) {
            float4 w0, w1, w2v, w3;
            if (ks < 15) {               // next-slice W loads (R4 verbatim)
                const float* Wr = W1 + (size_t)tid * 256 + (ks + 1) * 16;
                w0 = *(const float4*)(Wr + 0);
                w1 = *(const float4*)(Wr + 4);
                w2v = *(const float4*)(Wr + 8);
                w3 = *(const float4*)(Wr + 12);
            }
            const float* Wc = &Ws[ks & 1][0];
            const int kbase = ks << 4;
#pragma unroll
            for (int kk = 0; kk < 16; ++kk) {
                const float4 a0 = *(const float4*)&Al[(kbase + kk) * 64 + tg];
                const float4 a1 = *(const float4*)&Al[(kbase + kk) * 64 + tg + 4];
                const float4 b0 = *(const float4*)&Wc[kk * 256 + h4];
                const float4 b1 = *(const float4*)&Wc[kk * 256 + h4 + 128];
                const float avr[8] = {a0.x, a0.y, a0.z, a0.w, a1.x, a1.y, a1.z, a1.w};
                const float bvr[8] = {b0.x, b0.y, b0.z, b0.w, b1.x, b1.y, b1.z, b1.w};
#pragma unroll
                for (int i = 0; i < 8; ++i)
#pragma unroll
                    for (int j = 0; j < 8; ++j)
                        acc[i][j] += avr[i] * bvr[j];
            }
            if (ks < 15) {               // LDS writes after FMAs (R4 verbatim)
                float* Wd = &Ws[(ks + 1) & 1][0];
                Wd[ 0*256+tid]=w0.x; Wd[ 1*256+tid]=w0.y; Wd[ 2*256+tid]=w0.z; Wd[ 3*256+tid]=w0.w;
                Wd[ 4*256+tid]=w1.x; Wd[ 5*256+tid]=w1.y; Wd[ 6*256+tid]=w1.z; Wd[ 7*256+tid]=w1.w;
                Wd[ 8*256+tid]=w2v.x; Wd[ 9*256+tid]=w2v.y; Wd[10*256+tid]=w2v.z; Wd[11*256+tid]=w2v.w;
                Wd[12*256+tid]=w3.x; Wd[13*256+tid]=w3.y; Wd[14*256+tid]=w3.z; Wd[15*256+tid]=w3.w;
            }
            SOFT_BAR();                  // also separates ks=15 Al reads from I-write
        }

        // ---------------- phase I: acc -> Al as I[t][n] ----------------
#pragma unroll
        for (int i = 0; i < 8; ++i) {
            const int t = tg + i;
            *(float4*)&Al[t * 256 + h4] =
                make_float4(acc[i][0], acc[i][1], acc[i][2], acc[i][3]);
            *(float4*)&Al[t * 256 + h4 + 128] =
                make_float4(acc[i][4], acc[i][5], acc[i][6], acc[i][7]);
        }
        SOFT_BAR();

        // ---------------- async A: issue next chunk's X loads (early) -------
        if (cc + 1 < NCHUNK) {
            const int t0n    = (cc + 1) * TW;
            const int validn = (T_ - t0n < TW) ? (T_ - t0n) : TW;
            const int tsrc   = t0n + ((tl < validn) ? tl : (validn - 1));
            const float* Xrow = Xb + (size_t)tsrc * 256;
#pragma unroll
            for (int r = 0; r < 16; ++r)
                ra[r] = *(const float4*)(Xrow + r * 16 + wq);
        }

        // ---------------- phase S: scan (fmaf-PINNED, R14 verbatim) ---------
        {
            float Inx = Al[tid];         // q=0 prefetch
            for (int q = 0; q < valid; ++q) {
                const float Icur = Inx;
                if (q + 1 < valid) Inx = Al[(q + 1) * 256 + tid];
                const int t = t0 + q;
                const size_t pbase = (size_t)t * STP_ + boff;

                // canonical explicit-fma form (pinned):
                const float m1 = v2_ * v;
                const float t2 = v1_ * v;
                const float P  = __builtin_fmaf(m1, v, t2);
                const float Q  = (P + v0_) - u;
                const float vm = v + (Q + Icur);
                const float tb = __builtin_fmaf(b_, v, -u);
                const float um = __builtin_fmaf(coef, tb, u);

                const bool  sp = (vm - th_) > 0.f;
                const float s  = sp ? 1.f : 0.f;
                v = sp ? c_ : vm;        // == vm*(1-s)+s*c exactly, s in {0,1}
                u = sp ? (um + d_) : um; // == um + s*d

                states[pbase]           = v;
                states[pbase + BN_]     = u;
                states[pbase + 2 * BN_] = s;
                out_s[(size_t)t * BN_ + boff] = s;

                const unsigned long long mset = __ballot(sp);
                if (lane == 0) dotm[t][w] = mset;
            }
        }
        SOFT_BAR();                      // Al reads done before next A-stage
    }

    // ---------------- masks -> per-wave dots (parallel) ----------------
    for (int p = tid; p < T_ * 4; p += 256) {
        const int t  = p >> 2;
        const int ww = p & 3;
        unsigned long long m = dotm[t][ww];
        const float* wl = &w2l[ww << 6];
        float sum = 0.f;
        while (m) {
            const int i = __builtin_ctzll(m);
            sum += wl[i];
            m &= (m - 1);
        }
        dotf[t][ww] = sum;
    }
    __syncthreads();

    // ---------------- li recurrence (thread 0) ----------------
    if (tid == 0) {
        const float lk_  = pleak[0];
        const float olk_ = 1.0f - lk_;
        float li = st_li[bb];
        for (int t = 0; t < T_; ++t) {
            const float dot = (dotf[t][0] + dotf[t][1]) + (dotf[t][2] + dotf[t][3]);
            li = lk_ * li + olk_ * dot;
            out_dec[(size_t)t * 256 + bb] = li;
        }
    }
}

// ---------------------------------------------------------------------------
extern "C" void kernel_launch(void* const* d_in, const int* in_sizes, int n_in,
                              void* d_out, int out_size, void* d_ws, size_t ws_size,
                              hipStream_t stream) {
    const float* input  = (const float*)d_in[0];   // [B,T,N]
    const float* st_snn = (const float*)d_in[1];   // [3,B,N]
    const float* st_li  = (const float*)d_in[2];   // [B,1]
    const float* W1     = (const float*)d_in[3];   // [N,N]
    const float* W2     = (const float*)d_in[4];   // [1,N]
    const float* pa     = (const float*)d_in[5];
    const float* pb     = (const float*)d_in[6];
    const float* pc     = (const float*)d_in[7];
    const float* pd     = (const float*)d_in[8];
    const float* pv0    = (const float*)d_in[9];
    const float* pv1    = (const float*)d_in[10];
    const float* pv2    = (const float*)d_in[11];
    const float* ptau   = (const float*)d_in[12];
    const float* pth    = (const float*)d_in[13];
    const float* pleak  = (const float*)d_in[14];

    float* out        = (float*)d_out;
    float* out_s      = out;                                        // [500,256,256]
    float* out_states = out + (size_t)T_ * BN_;                     // [500,3,256,256]
    float* out_dec    = out + (size_t)T_ * BN_ + (size_t)T_ * STP_; // [500,256]

    fused_snn_kernel<<<dim3(B_), dim3(256), 0, stream>>>(
        input, W1, out_s, out_states, out_dec, st_snn, st_li, W2,
        pa, pb, pc, pd, pv0, pv1, pv2, ptau, pth, pleak);
}

// Round 17
// 362.408 us; speedup vs baseline: 1.2739x; 1.0714x over previous
//
#include <hip/hip_runtime.h>

#define B_ 256
#define T_ 500
#define N_ 256
#define BN_ 65536            // B_*N_
#define STP_ 196608          // 3*B_*N_ (states per-t stride)
#define TW 64                // t-window per chunk
#define NCHUNK 8             // ceil(500/64)

// Soft barrier: LDS-visibility sync without vmcnt(0) store drain (stores have
// no in-kernel consumer). sched_barrier fences per rule #18.
#define SOFT_BAR() do {                                   \
    __builtin_amdgcn_sched_barrier(0);                    \
    asm volatile("s_waitcnt lgkmcnt(0)" ::: "memory");    \
    __builtin_amdgcn_s_barrier();                         \
    __builtin_amdgcn_sched_barrier(0);                    \
} while (0)

// ---------------------------------------------------------------------------
// Fused GEMM + Izhikevich scan, chunk-PIPELINED. One block per batch b.
// LDS: Xl (X of chunk c, [k][t]) + Il (I of chunk c-1, [t][n]) + Ws (BK=8
// dbuf) + dotm = 163.4 KB. Per ks-slice of chunk c's GEMM, 2 scan steps of
// chunk c-1 run interleaved -> the scan's 4 stores/step drain under the
// FMA/LDS-pipe work (R16 showed S is store-backpressure-bound ~82 us when
// serialized as its own phase). GEMM chain k-ascending (ks32 x kk8 == R14's
// ks16 x kk16 order) -> bit-identical I. Scan text = R14-PINNED fmaf form
// (proven context-immune through 3 restructures). SOFT_BARs so stores never
// force-drain at the 32 barriers/chunk.
// ---------------------------------------------------------------------------
__global__ __launch_bounds__(256)
void fused_snn_kernel(const float* __restrict__ X, const float* __restrict__ W1,
                      float* __restrict__ out_s, float* __restrict__ states,
                      float* __restrict__ out_dec,
                      const float* __restrict__ st_snn, const float* __restrict__ st_li,
                      const float* __restrict__ W2,
                      const float* __restrict__ pa, const float* __restrict__ pb,
                      const float* __restrict__ pc, const float* __restrict__ pd,
                      const float* __restrict__ pv0, const float* __restrict__ pv1,
                      const float* __restrict__ pv2, const float* __restrict__ ptau,
                      const float* __restrict__ pth, const float* __restrict__ pleak) {
    __shared__ float Xl[TW * 256];              // 64 KB: X chunk c, [k][t]
    __shared__ float Il[TW * 256];              // 64 KB: I chunk c-1, [t][n]
    __shared__ float Ws[2][8 * 256];            // 16 KB: W1t BK=8 slice dbuf
    __shared__ unsigned long long dotm[T_][4];  // 16000 B: per-wave spike masks

    const int bb   = blockIdx.x;
    const int tid  = threadIdx.x;
    const int w    = tid >> 6;
    const int lane = tid & 63;
    const int boff = bb * 256 + tid;

    // scan per-thread state & params
    float v = st_snn[boff];
    float u = st_snn[BN_ + boff];
    const float a_   = pa[tid];
    const float b_   = pb[tid];
    const float c_   = pc[tid];
    const float d_   = pd[tid];
    const float v0_  = pv0[tid];
    const float v1_  = pv1[tid];
    const float v2_  = pv2[tid];
    const float coef = (1.0f / ptau[tid]) * a_;  // (DT/tau_u)*a, DT=1
    const float th_  = pth[tid];

    // GEMM microtile: 8 t-groups x 32 n-groups, 8x8 per thread
    const int g   = tid >> 5;            // t rows 8g..8g+7
    const int tg  = g << 3;
    const int h4  = (tid & 31) << 2;     // n cols h4..h4+3 and h4+128..h4+131

    const float* Xb = X + (size_t)bb * (T_ * 256);
    const int tl = tid & 63;             // X-stage t_loc
    const int wq = (tid >> 6) << 2;      // X-stage k sub-quad

    // W slice 0 (k 0..7) held permanently in regs (chunk-invariant)
    const float* Wr0 = W1 + (size_t)tid * 256;
    const float4 z0 = *(const float4*)(Wr0 + 0);
    const float4 z1 = *(const float4*)(Wr0 + 4);

    // stage X chunk 0 (valid=64) and W slice 0
    float4 ra[16];
    {
        const float* Xrow = Xb + (size_t)tl * 256;
#pragma unroll
        for (int r = 0; r < 16; ++r)
            ra[r] = *(const float4*)(Xrow + r * 16 + wq);
    }
#pragma unroll
    for (int r = 0; r < 16; ++r) {
        const int k = r * 16 + wq;
        Xl[(k + 0) * 64 + tl] = ra[r].x;
        Xl[(k + 1) * 64 + tl] = ra[r].y;
        Xl[(k + 2) * 64 + tl] = ra[r].z;
        Xl[(k + 3) * 64 + tl] = ra[r].w;
    }
    {
        float* Wd = &Ws[0][0];
        Wd[0*256+tid]=z0.x; Wd[1*256+tid]=z0.y; Wd[2*256+tid]=z0.z; Wd[3*256+tid]=z0.w;
        Wd[4*256+tid]=z1.x; Wd[5*256+tid]=z1.y; Wd[6*256+tid]=z1.z; Wd[7*256+tid]=z1.w;
    }
    SOFT_BAR();

    float Inx = 0.f;                     // scan I-prefetch register

    for (int cc = 0; cc < NCHUNK; ++cc) {
        const int tb = (cc - 1) * TW;    // scan chunk base (used when cc>0)

        float acc[8][8];
#pragma unroll
        for (int i = 0; i < 8; ++i)
#pragma unroll
            for (int j = 0; j < 8; ++j) acc[i][j] = 0.f;

        for (int ks = 0; ks < 32; ++ks) {
            float4 q0, q1;
            if (ks < 31) {               // next W slice (k 8(ks+1)..+8) from L2
                const float* Wr = W1 + (size_t)tid * 256 + (ks + 1) * 8;
                q0 = *(const float4*)(Wr);
                q1 = *(const float4*)(Wr + 4);
            }
            if (ks == 24 && cc + 1 < NCHUNK) {   // issue next-chunk X loads
                const int t0n    = (cc + 1) * TW;
                const int validn = (T_ - t0n < TW) ? (T_ - t0n) : TW;
                const int tsrc   = t0n + ((tl < validn) ? tl : (validn - 1));
                const float* Xrow = Xb + (size_t)tsrc * 256;
#pragma unroll
                for (int r = 0; r < 16; ++r)
                    ra[r] = *(const float4*)(Xrow + r * 16 + wq);
            }
            const float* Wc = &Ws[ks & 1][0];
            const int kbase = ks << 3;
#pragma unroll
            for (int kk = 0; kk < 8; ++kk) {
                const float4 a0 = *(const float4*)&Xl[(kbase + kk) * 64 + tg];
                const float4 a1 = *(const float4*)&Xl[(kbase + kk) * 64 + tg + 4];
                const float4 b0 = *(const float4*)&Wc[kk * 256 + h4];
                const float4 b1 = *(const float4*)&Wc[kk * 256 + h4 + 128];
                const float avr[8] = {a0.x, a0.y, a0.z, a0.w, a1.x, a1.y, a1.z, a1.w};
                const float bvr[8] = {b0.x, b0.y, b0.z, b0.w, b1.x, b1.y, b1.z, b1.w};
#pragma unroll
                for (int i = 0; i < 8; ++i)
#pragma unroll
                    for (int j = 0; j < 8; ++j)
                        acc[i][j] += avr[i] * bvr[j];
            }
            // interleaved scan: 2 steps of chunk cc-1 (stores drain under GEMM)
            if (cc > 0) {
#pragma unroll
                for (int e = 0; e < 2; ++e) {
                    const int q = (ks << 1) + e;
                    const float Icur = Inx;
                    if (q + 1 < TW) Inx = Il[(q + 1) * 256 + tid];
                    const int t = tb + q;
                    const size_t pbase = (size_t)t * STP_ + boff;

                    // canonical explicit-fma form (pinned, R14 verbatim):
                    const float m1 = v2_ * v;
                    const float t2 = v1_ * v;
                    const float P  = __builtin_fmaf(m1, v, t2);
                    const float Q  = (P + v0_) - u;
                    const float vm = v + (Q + Icur);
                    const float tb2 = __builtin_fmaf(b_, v, -u);
                    const float um = __builtin_fmaf(coef, tb2, u);

                    const bool  sp = (vm - th_) > 0.f;
                    const float s  = sp ? 1.f : 0.f;
                    v = sp ? c_ : vm;        // == vm*(1-s)+s*c exactly
                    u = sp ? (um + d_) : um; // == um + s*d

                    states[pbase]           = v;
                    states[pbase + BN_]     = u;
                    states[pbase + 2 * BN_] = s;
                    out_s[(size_t)t * BN_ + boff] = s;

                    const unsigned long long mset = __ballot(sp);
                    if (lane == 0) dotm[t][w] = mset;
                }
            }
            if (ks < 31) {               // write next W slice after FMAs
                float* Wd = &Ws[(ks + 1) & 1][0];
                Wd[0*256+tid]=q0.x; Wd[1*256+tid]=q0.y; Wd[2*256+tid]=q0.z; Wd[3*256+tid]=q0.w;
                Wd[4*256+tid]=q1.x; Wd[5*256+tid]=q1.y; Wd[6*256+tid]=q1.z; Wd[7*256+tid]=q1.w;
            }
            SOFT_BAR();
        }

        // chunk end: acc -> Il (scan of cc-1 fully consumed Il; barrier above)
#pragma unroll
        for (int i = 0; i < 8; ++i) {
            const int t = tg + i;
            *(float4*)&Il[t * 256 + h4] =
                make_float4(acc[i][0], acc[i][1], acc[i][2], acc[i][3]);
            *(float4*)&Il[t * 256 + h4 + 128] =
                make_float4(acc[i][4], acc[i][5], acc[i][6], acc[i][7]);
        }
        if (cc + 1 < NCHUNK) {           // next chunk's X (regs, issued ks=24)
#pragma unroll
            for (int r = 0; r < 16; ++r) {
                const int k = r * 16 + wq;
                Xl[(k + 0) * 64 + tl] = ra[r].x;
                Xl[(k + 1) * 64 + tl] = ra[r].y;
                Xl[(k + 2) * 64 + tl] = ra[r].z;
                Xl[(k + 3) * 64 + tl] = ra[r].w;
            }
            float* Wd = &Ws[0][0];       // restage W slice 0 from held regs
            Wd[0*256+tid]=z0.x; Wd[1*256+tid]=z0.y; Wd[2*256+tid]=z0.z; Wd[3*256+tid]=z0.w;
            Wd[4*256+tid]=z1.x; Wd[5*256+tid]=z1.y; Wd[6*256+tid]=z1.z; Wd[7*256+tid]=z1.w;
        }
        SOFT_BAR();
        Inx = Il[tid];                   // prefetch first I of chunk cc's scan
    }

    // epilogue: scan chunk 7 (52 steps), not overlapped
    {
        const int tbE = 7 * TW;          // 448
        for (int q = 0; q < 52; ++q) {
            const float Icur = Inx;
            if (q + 1 < 52) Inx = Il[(q + 1) * 256 + tid];
            const int t = tbE + q;
            const size_t pbase = (size_t)t * STP_ + boff;

            const float m1 = v2_ * v;
            const float t2 = v1_ * v;
            const float P  = __builtin_fmaf(m1, v, t2);
            const float Q  = (P + v0_) - u;
            const float vm = v + (Q + Icur);
            const float tb2 = __builtin_fmaf(b_, v, -u);
            const float um = __builtin_fmaf(coef, tb2, u);

            const bool  sp = (vm - th_) > 0.f;
            const float s  = sp ? 1.f : 0.f;
            v = sp ? c_ : vm;
            u = sp ? (um + d_) : um;

            states[pbase]           = v;
            states[pbase + BN_]     = u;
            states[pbase + 2 * BN_] = s;
            out_s[(size_t)t * BN_ + boff] = s;

            const unsigned long long mset = __ballot(sp);
            if (lane == 0) dotm[t][w] = mset;
        }
    }
    __syncthreads();                     // dotm complete

    // masks -> dots (w2l/dotf overlay on dead Ws region: 256+2000 <= 4096 floats)
    float* scr  = &Ws[0][0];
    float* w2l  = scr;                   // [256]
    float* dotf = scr + 256;             // [500][4]
    w2l[tid] = W2[tid];
    __syncthreads();
    for (int p = tid; p < T_ * 4; p += 256) {
        const int t  = p >> 2;
        const int ww = p & 3;
        unsigned long long m = dotm[t][ww];
        const float* wl = &w2l[ww << 6];
        float sum = 0.f;
        while (m) {
            const int i = __builtin_ctzll(m);
            sum += wl[i];
            m &= (m - 1);
        }
        dotf[t * 4 + ww] = sum;
    }
    __syncthreads();

    if (tid == 0) {
        const float lk_  = pleak[0];
        const float olk_ = 1.0f - lk_;
        float li = st_li[bb];
        for (int t = 0; t < T_; ++t) {
            const float dot = (dotf[t*4+0] + dotf[t*4+1]) + (dotf[t*4+2] + dotf[t*4+3]);
            li = lk_ * li + olk_ * dot;
            out_dec[(size_t)t * 256 + bb] = li;
        }
    }
}

// ---------------------------------------------------------------------------
extern "C" void kernel_launch(void* const* d_in, const int* in_sizes, int n_in,
                              void* d_out, int out_size, void* d_ws, size_t ws_size,
                              hipStream_t stream) {
    const float* input  = (const float*)d_in[0];   // [B,T,N]
    const float* st_snn = (const float*)d_in[1];   // [3,B,N]
    const float* st_li  = (const float*)d_in[2];   // [B,1]
    const float* W1     = (const float*)d_in[3];   // [N,N]
    const float* W2     = (const float*)d_in[4];   // [1,N]
    const float* pa     = (const float*)d_in[5];
    const float* pb     = (const float*)d_in[6];
    const float* pc     = (const float*)d_in[7];
    const float* pd     = (const float*)d_in[8];
    const float* pv0    = (const float*)d_in[9];
    const float* pv1    = (const float*)d_in[10];
    const float* pv2    = (const float*)d_in[11];
    const float* ptau   = (const float*)d_in[12];
    const float* pth    = (const float*)d_in[13];
    const float* pleak  = (const float*)d_in[14];

    float* out        = (float*)d_out;
    float* out_s      = out;                                        // [500,256,256]
    float* out_states = out + (size_t)T_ * BN_;                     // [500,3,256,256]
    float* out_dec    = out + (size_t)T_ * BN_ + (size_t)T_ * STP_; // [500,256]

    fused_snn_kernel<<<dim3(B_), dim3(256), 0, stream>>>(
        input, W1, out_s, out_states, out_dec, st_snn, st_li, W2,
        pa, pb, pc, pd, pv0, pv1, pv2, ptau, pth, pleak);
}